// Round 9
// baseline (542.311 us; speedup 1.0000x reference)
//
#include <hip/hip_runtime.h>

typedef unsigned short u16;
typedef unsigned int   u32;
typedef __attribute__((ext_vector_type(8))) short short8;   // 8 x bf16
typedef __attribute__((ext_vector_type(4))) float f32x4;

__device__ __forceinline__ float b2f(u16 u) {
  union { float f; u32 i; } v; v.i = ((u32)u) << 16; return v.f;
}
__device__ __forceinline__ u16 f2b(float f) {
  union { float f; u32 i; } v; v.f = f;
  u32 r = v.i + 0x7fffu + ((v.i >> 16) & 1u);   // RNE
  return (u16)(r >> 16);
}

__device__ __forceinline__ void gload_lds16(const void* g, void* l) {
  __builtin_amdgcn_global_load_lds(
      (const __attribute__((address_space(1))) void*)g,
      (__attribute__((address_space(3))) void*)l, 16, 0, 0);
}

template <int N> __device__ __forceinline__ void wait_vmcnt() {
  if constexpr (N == 0)      asm volatile("s_waitcnt vmcnt(0)" ::: "memory");
  else if constexpr (N == 2) asm volatile("s_waitcnt vmcnt(2)" ::: "memory");
  else if constexpr (N == 3) asm volatile("s_waitcnt vmcnt(3)" ::: "memory");
  else if constexpr (N == 6) asm volatile("s_waitcnt vmcnt(6)" ::: "memory");
  else static_assert(N < 0, "unsupported vmcnt literal");
}

// ---------------- f32 -> bf16 converts ----------------
__device__ __forceinline__ ushort4 cvt4(float4 v) {
  ushort4 o;
  o.x = f2b(v.x); o.y = f2b(v.y); o.z = f2b(v.z); o.w = f2b(v.w);
  return o;
}

__global__ __launch_bounds__(256) void cvt_hp(const float* __restrict__ hs,
                                              const float* __restrict__ wp,
                                              u16* __restrict__ h_bf,
                                              u16* __restrict__ wp_bf) {
  const long H4 = 2097152, W4 = 12582912;   // float4 counts
  for (long i = (long)blockIdx.x * 256 + threadIdx.x; i < H4 + W4;
       i += (long)gridDim.x * 256) {
    if (i < H4)
      ((ushort4*)h_bf)[i] = cvt4(((const float4*)hs)[i]);
    else
      ((ushort4*)wp_bf)[i - H4] = cvt4(((const float4*)wp)[i - H4]);
  }
}

__global__ __launch_bounds__(256) void cvt_bf16(const float* __restrict__ in,
                                                u16* __restrict__ out, int n4) {
  for (long i = (long)blockIdx.x * 256 + threadIdx.x; i < n4; i += (long)gridDim.x * 256)
    ((ushort4*)out)[i] = cvt4(((const float4*)in)[i]);
}

__device__ __forceinline__ short8 frag_ld64(const u16* base, int rbase, int kk,
                                            int fr, int fq) {
  const int r = rbase + fr;
  return *(const short8*)(base + r * 64 + ((((kk << 2) + fq) ^ (r & 7)) << 3));
}

// ============ GEMM1: 4-phase, tile 256x192 (proven R7, unchanged) ==========
__global__ __launch_bounds__(512, 2) void gemm8p(const u16* __restrict__ A,
                                                 const u16* __restrict__ B,
                                                 u16* __restrict__ Cq,
                                                 u16* __restrict__ VT,
                                                 int M, int N, int K) {
  constexpr int AE = 16384;                 // A region u16 (256x64)
  constexpr int BUFSZ = AE + 12288;         // + B region (192x64) = 28672 u16
  __shared__ u16 lds[2 * BUFSZ];            // 114,688 B
  const int tid = threadIdx.x;
  const int wid = tid >> 6, lane = tid & 63;
  const int fr = lane & 15, fq = lane >> 4;
  const int mA = (wid >> 2) * 128;          // wm in {0,1}
  const int nB = (wid & 3) * 48;            // wn in {0..3}

  const int nty = M >> 8;                   // 8
  const int qx = gridDim.x >> 3;
  const int wg = (blockIdx.x & 7) * qx + (blockIdx.x >> 3);
  const int by = wg % nty, bx = wg / nty;
  const long row0 = (long)by * 256, col0 = (long)bx * 192;

  const int rr8 = tid >> 3;
  const int jl = (tid & 7) ^ (rr8 & 7);
  const u16* gA = A + (row0 + rr8) * (long)K + jl * 8;
  const u16* gB = B + (col0 + rr8) * (long)K + jl * 8;

  f32x4 acc[8][3];
#pragma unroll
  for (int m = 0; m < 8; ++m)
#pragma unroll
    for (int n = 0; n < 3; ++n) acc[m][n] = f32x4{0.f, 0.f, 0.f, 0.f};

  const int NT = K >> 6;                    // BK = 64

  auto stageA = [&](int i, int t) {
    gload_lds16(gA + (long)(i * 64) * K + (long)t * 64,
                lds + (t & 1) * BUFSZ + (i * 512 + tid) * 8);
  };
  auto stageB = [&](int i, int t) {
    gload_lds16(gB + (long)(i * 64) * K + (long)t * 64,
                lds + (t & 1) * BUFSZ + AE + (i * 512 + tid) * 8);
  };

#pragma unroll
  for (int i = 0; i < 4; ++i) stageA(i, 0);
#pragma unroll
  for (int i = 0; i < 3; ++i) stageB(i, 0);
#pragma unroll
  for (int i = 0; i < 3; ++i) stageB(i, 1);
  wait_vmcnt<3>();
  __builtin_amdgcn_s_barrier();

  for (int t = 0; t < NT; ++t) {
    const u16* SA = lds + (t & 1) * BUFSZ;
    const u16* SB = SA + AE;
    short8 a0[4], a1[4], b0[3], b1[3];

    // ---- phase 1: (qm0,kk0); all B frags; stage A i=0,1 ----
#pragma unroll
    for (int m = 0; m < 4; ++m) a0[m] = frag_ld64(SA, mA + m * 16, 0, fr, fq);
#pragma unroll
    for (int n = 0; n < 3; ++n) b0[n] = frag_ld64(SB, nB + n * 16, 0, fr, fq);
#pragma unroll
    for (int n = 0; n < 3; ++n) b1[n] = frag_ld64(SB, nB + n * 16, 1, fr, fq);
    if (t + 1 < NT) { stageA(0, t + 1); stageA(1, t + 1); }
    __builtin_amdgcn_s_setprio(1);
#pragma unroll
    for (int m = 0; m < 4; ++m)
#pragma unroll
      for (int n = 0; n < 3; ++n)
        acc[m][n] = __builtin_amdgcn_mfma_f32_16x16x32_bf16(a0[m], b0[n], acc[m][n], 0, 0, 0);
    __builtin_amdgcn_s_setprio(0);
    asm volatile("s_waitcnt lgkmcnt(0)" ::: "memory");   // all B(t) reads retired
    __builtin_amdgcn_s_barrier();

    // ---- phase 2: (qm1,kk0); stage A i=2,3 ----
#pragma unroll
    for (int m = 0; m < 4; ++m) a1[m] = frag_ld64(SA, mA + 64 + m * 16, 0, fr, fq);
    if (t + 1 < NT) { stageA(2, t + 1); stageA(3, t + 1); }
    __builtin_amdgcn_s_setprio(1);
#pragma unroll
    for (int m = 0; m < 4; ++m)
#pragma unroll
      for (int n = 0; n < 3; ++n)
        acc[4 + m][n] = __builtin_amdgcn_mfma_f32_16x16x32_bf16(a1[m], b0[n], acc[4 + m][n], 0, 0, 0);
    __builtin_amdgcn_s_setprio(0);
    __builtin_amdgcn_s_barrier();

    // ---- phase 3: (qm0,kk1); stage B i=0,1 into buf(t) B-region ----
#pragma unroll
    for (int m = 0; m < 4; ++m) a0[m] = frag_ld64(SA, mA + m * 16, 1, fr, fq);
    if (t + 2 < NT) { stageB(0, t + 2); stageB(1, t + 2); }
    __builtin_amdgcn_s_setprio(1);
#pragma unroll
    for (int m = 0; m < 4; ++m)
#pragma unroll
      for (int n = 0; n < 3; ++n)
        acc[m][n] = __builtin_amdgcn_mfma_f32_16x16x32_bf16(a0[m], b1[n], acc[m][n], 0, 0, 0);
    __builtin_amdgcn_s_setprio(0);
    __builtin_amdgcn_s_barrier();

    // ---- phase 4: (qm1,kk1); stage B i=2; counted vmcnt ----
#pragma unroll
    for (int m = 0; m < 4; ++m) a1[m] = frag_ld64(SA, mA + 64 + m * 16, 1, fr, fq);
    if (t + 2 < NT) stageB(2, t + 2);
    __builtin_amdgcn_s_setprio(1);
#pragma unroll
    for (int m = 0; m < 4; ++m)
#pragma unroll
      for (int n = 0; n < 3; ++n)
        acc[4 + m][n] = __builtin_amdgcn_mfma_f32_16x16x32_bf16(a1[m], b1[n], acc[4 + m][n], 0, 0, 0);
    __builtin_amdgcn_s_setprio(0);
    if (t + 2 < NT) wait_vmcnt<3>();
    else            wait_vmcnt<0>();
    __builtin_amdgcn_s_barrier();
  }

#pragma unroll
  for (int m = 0; m < 8; ++m)
#pragma unroll
    for (int n = 0; n < 3; ++n) {
      const long c = col0 + nB + n * 16 + fr;
      const long rb = row0 + mA + m * 16 + fq * 4;
      if (c >= 8192) {
        ushort4 o;
        o.x = f2b(acc[m][n][0]); o.y = f2b(acc[m][n][1]);
        o.z = f2b(acc[m][n][2]); o.w = f2b(acc[m][n][3]);
        *(ushort4*)(VT + (c - 8192) * 2048 + rb) = o;
      } else {
#pragma unroll
        for (int j = 0; j < 4; ++j) Cq[(rb + j) * N + c] = f2b(acc[m][n][j]);
      }
    }
}

// ============ GEMM2: 4-phase, tile 256x128 (R8, unchanged) ==================
__global__ __launch_bounds__(512, 2) void gemm2_4p(const u16* __restrict__ A,
                                                   const u16* __restrict__ B,
                                                   float* __restrict__ C,
                                                   int M, int N, int K) {
  constexpr int AE = 16384;                 // A region u16 (256x64)
  constexpr int BUFSZ = AE + 8192;          // + B region (128x64) = 24576 u16
  __shared__ u16 lds[2 * BUFSZ];            // 98,304 B
  const int tid = threadIdx.x;
  const int wid = tid >> 6, lane = tid & 63;
  const int fr = lane & 15, fq = lane >> 4;
  const int mA = (wid >> 2) * 128;          // wm in {0,1}
  const int nB = (wid & 3) * 32;            // wn in {0..3}

  const int nty = M >> 8;                   // 8
  const int qx = gridDim.x >> 3;
  const int wg = (blockIdx.x & 7) * qx + (blockIdx.x >> 3);
  const int by = wg % nty, bx = wg / nty;
  const long row0 = (long)by * 256, col0 = (long)bx * 128;

  const int rr8 = tid >> 3;
  const int jl = (tid & 7) ^ (rr8 & 7);
  const u16* gA = A + (row0 + rr8) * (long)K + jl * 8;
  const u16* gB = B + (col0 + rr8) * (long)K + jl * 8;

  f32x4 acc[8][2];
#pragma unroll
  for (int m = 0; m < 8; ++m)
#pragma unroll
    for (int n = 0; n < 2; ++n) acc[m][n] = f32x4{0.f, 0.f, 0.f, 0.f};

  const int NT = K >> 6;

  auto stageA = [&](int i, int t) {
    gload_lds16(gA + (long)(i * 64) * K + (long)t * 64,
                lds + (t & 1) * BUFSZ + (i * 512 + tid) * 8);
  };
  auto stageB = [&](int i, int t) {
    gload_lds16(gB + (long)(i * 64) * K + (long)t * 64,
                lds + (t & 1) * BUFSZ + AE + (i * 512 + tid) * 8);
  };

#pragma unroll
  for (int i = 0; i < 4; ++i) stageA(i, 0);
#pragma unroll
  for (int i = 0; i < 2; ++i) stageB(i, 0);
#pragma unroll
  for (int i = 0; i < 2; ++i) stageB(i, 1);
  wait_vmcnt<2>();
  __builtin_amdgcn_s_barrier();

  for (int t = 0; t < NT; ++t) {
    const u16* SA = lds + (t & 1) * BUFSZ;
    const u16* SB = SA + AE;
    short8 a0[4], a1[4], b0[2], b1[2];

    // ---- phase 1 ----
#pragma unroll
    for (int m = 0; m < 4; ++m) a0[m] = frag_ld64(SA, mA + m * 16, 0, fr, fq);
#pragma unroll
    for (int n = 0; n < 2; ++n) b0[n] = frag_ld64(SB, nB + n * 16, 0, fr, fq);
#pragma unroll
    for (int n = 0; n < 2; ++n) b1[n] = frag_ld64(SB, nB + n * 16, 1, fr, fq);
    if (t + 1 < NT) { stageA(0, t + 1); stageA(1, t + 1); }
    __builtin_amdgcn_s_setprio(1);
#pragma unroll
    for (int m = 0; m < 4; ++m)
#pragma unroll
      for (int n = 0; n < 2; ++n)
        acc[m][n] = __builtin_amdgcn_mfma_f32_16x16x32_bf16(a0[m], b0[n], acc[m][n], 0, 0, 0);
    __builtin_amdgcn_s_setprio(0);
    asm volatile("s_waitcnt lgkmcnt(0)" ::: "memory");   // all B(t) reads retired
    __builtin_amdgcn_s_barrier();

    // ---- phase 2 ----
#pragma unroll
    for (int m = 0; m < 4; ++m) a1[m] = frag_ld64(SA, mA + 64 + m * 16, 0, fr, fq);
    if (t + 1 < NT) { stageA(2, t + 1); stageA(3, t + 1); }
    __builtin_amdgcn_s_setprio(1);
#pragma unroll
    for (int m = 0; m < 4; ++m)
#pragma unroll
      for (int n = 0; n < 2; ++n)
        acc[4 + m][n] = __builtin_amdgcn_mfma_f32_16x16x32_bf16(a1[m], b0[n], acc[4 + m][n], 0, 0, 0);
    __builtin_amdgcn_s_setprio(0);
    __builtin_amdgcn_s_barrier();

    // ---- phase 3 ----
#pragma unroll
    for (int m = 0; m < 4; ++m) a0[m] = frag_ld64(SA, mA + m * 16, 1, fr, fq);
    if (t + 2 < NT) stageB(0, t + 2);
    __builtin_amdgcn_s_setprio(1);
#pragma unroll
    for (int m = 0; m < 4; ++m)
#pragma unroll
      for (int n = 0; n < 2; ++n)
        acc[m][n] = __builtin_amdgcn_mfma_f32_16x16x32_bf16(a0[m], b1[n], acc[m][n], 0, 0, 0);
    __builtin_amdgcn_s_setprio(0);
    __builtin_amdgcn_s_barrier();

    // ---- phase 4 ----
#pragma unroll
    for (int m = 0; m < 4; ++m) a1[m] = frag_ld64(SA, mA + 64 + m * 16, 1, fr, fq);
    if (t + 2 < NT) stageB(1, t + 2);
    __builtin_amdgcn_s_setprio(1);
#pragma unroll
    for (int m = 0; m < 4; ++m)
#pragma unroll
      for (int n = 0; n < 2; ++n)
        acc[4 + m][n] = __builtin_amdgcn_mfma_f32_16x16x32_bf16(a1[m], b1[n], acc[4 + m][n], 0, 0, 0);
    __builtin_amdgcn_s_setprio(0);
    if (t + 2 < NT) wait_vmcnt<2>();
    else            wait_vmcnt<0>();
    __builtin_amdgcn_s_barrier();
  }

#pragma unroll
  for (int m = 0; m < 8; ++m)
#pragma unroll
    for (int n = 0; n < 2; ++n)
#pragma unroll
      for (int j = 0; j < 4; ++j) {
        const long r = row0 + mA + m * 16 + fq * 4 + j;
        const long c = col0 + nB + n * 16 + fr;
        C[r * N + c] = acc[m][n][j];
      }
}

// ---------------- RoPE on q,k (vectorized) ---------------------------------
__global__ __launch_bounds__(256) void rope_qk(u16* __restrict__ qkv,
                                               const float* __restrict__ cosb,
                                               const float* __restrict__ sinb) {
  const int idx = blockIdx.x * 256 + threadIdx.x;   // grid exact: 2,097,152
  const int dq  = idx & 15;
  const int h   = (idx >> 4) & 31;
  const int seg = (idx >> 9) & 1;                   // 0 = q, 1 = k
  const int s   = idx >> 10;
  const int d0  = dq * 4;
  u16* base = qkv + (long)s * 12288 + seg * 4096 + h * 128;
  const ushort4 x1 = *(const ushort4*)(base + d0);
  const ushort4 x2 = *(const ushort4*)(base + d0 + 64);
  const float4 c1 = *(const float4*)(cosb + s * 128 + d0);
  const float4 s1 = *(const float4*)(sinb + s * 128 + d0);
  const float4 c2 = *(const float4*)(cosb + s * 128 + d0 + 64);
  const float4 s2 = *(const float4*)(sinb + s * 128 + d0 + 64);
  const float scale = seg ? 1.0f : 0.08838834764831845f;   // 1/sqrt(128) on q
  float x1f[4] = {b2f(x1.x), b2f(x1.y), b2f(x1.z), b2f(x1.w)};
  float x2f[4] = {b2f(x2.x), b2f(x2.y), b2f(x2.z), b2f(x2.w)};
  const float c1a[4] = {c1.x, c1.y, c1.z, c1.w}, s1a[4] = {s1.x, s1.y, s1.z, s1.w};
  const float c2a[4] = {c2.x, c2.y, c2.z, c2.w}, s2a[4] = {s2.x, s2.y, s2.z, s2.w};
  ushort4 o1, o2;
  u16* o1p = (u16*)&o1; u16* o2p = (u16*)&o2;
#pragma unroll
  for (int j = 0; j < 4; ++j) {
    o1p[j] = f2b((x1f[j] * c1a[j] - x2f[j] * s1a[j]) * scale);
    o2p[j] = f2b((x2f[j] * c2a[j] + x1f[j] * s2a[j]) * scale);
  }
  *(ushort4*)(base + d0) = o1;
  *(ushort4*)(base + d0 + 64) = o2;
}

// ---------------- causal flash attention (QBLK=128, 32 q-rows/wave) ---------
// grid (16, 32), 256 thr = 4 waves; wave owns 32 q-rows (2 x 16-row frags).
// 2x MFMA per LDS byte vs QBLK=64; halved K/V staging. Fully-masked waves
// skip compute (wave-uniform guard; barriers stay block-wide).
__global__ __launch_bounds__(256) void attn_fwd(const u16* __restrict__ Qb,
                                                const u16* __restrict__ Kb,
                                                const u16* __restrict__ Vt,
                                                u16* __restrict__ Ob) {
  const int h  = blockIdx.y;
  const int bxr = gridDim.x - 1 - blockIdx.x;   // longest blocks dispatch first
  const int q0 = bxr * 128;
  const int tid = threadIdx.x;
  const int wid = tid >> 6, lane = tid & 63;
  const int fr = lane & 15, fq = lane >> 4;

  __shared__ u16 Ks[64 * 128];     // 16 KB
  __shared__ u16 Vts[128 * 64];    // 16 KB
  __shared__ u16 Ps[4][32 * 72];   // 18.4 KB  (total 50.4 KB -> 3 blocks/CU)

  auto stage = [&](int t) {
    const int kv0 = t * 64;
#pragma unroll
    for (int i = 0; i < 4; ++i) {
      const int c = wid * 4 + i;
      {
        const int r = c * 4 + (lane >> 4);
        const int p = lane & 15;
        const int jsrc = p ^ (r & 7);
        gload_lds16(Kb + (long)(kv0 + r) * 12288 + h * 128 + jsrc * 8,
                    (char*)Ks + c * 1024);
      }
      {
        const int d = c * 8 + (lane >> 3);
        const int p = lane & 7;
        const int jsrc = p ^ (d & 7);
        gload_lds16(Vt + (long)(h * 128 + d) * 2048 + kv0 + jsrc * 8,
                    (char*)Vts + c * 1024);
      }
    }
  };

  short8 qf[2][4];
#pragma unroll
  for (int m = 0; m < 2; ++m) {
    const long qrow = q0 + wid * 32 + m * 16 + fr;
#pragma unroll
    for (int kk = 0; kk < 4; ++kk)
      qf[m][kk] = *(const short8*)(Qb + qrow * 12288 + h * 128 + kk * 32 + fq * 8);
  }

  f32x4 Oacc[2][8];
#pragma unroll
  for (int m = 0; m < 2; ++m)
#pragma unroll
    for (int f = 0; f < 8; ++f) Oacc[m][f] = f32x4{0.f, 0.f, 0.f, 0.f};
  float mrun[2][4], lrun[2][4];
#pragma unroll
  for (int m = 0; m < 2; ++m)
#pragma unroll
    for (int j = 0; j < 4; ++j) { mrun[m][j] = -1e30f; lrun[m][j] = 0.f; }

  const int nt = 2 * bxr + 2;
  const int wq_hi = q0 + wid * 32 + 31;   // wave's max q row

  for (int t = 0; t < nt; ++t) {
    const int kv0 = t * 64;
    stage(t);
    __syncthreads();

    if (kv0 <= wq_hi) {                    // wave-uniform causal skip
      // ---- QK^T: S[2 m][4 n] ----
      f32x4 S[2][4];
#pragma unroll
      for (int m = 0; m < 2; ++m)
#pragma unroll
        for (int n = 0; n < 4; ++n) S[m][n] = f32x4{0.f, 0.f, 0.f, 0.f};
#pragma unroll
      for (int kk = 0; kk < 4; ++kk) {
        short8 kf[4];
#pragma unroll
        for (int n = 0; n < 4; ++n) {
          const int r = n * 16 + fr;
          const int p = (kk * 4 + fq) ^ (r & 7);
          kf[n] = *(const short8*)((const char*)Ks + r * 256 + p * 16);
        }
#pragma unroll
        for (int m = 0; m < 2; ++m)
#pragma unroll
          for (int n = 0; n < 4; ++n)
            S[m][n] = __builtin_amdgcn_mfma_f32_16x16x32_bf16(qf[m][kk], kf[n], S[m][n], 0, 0, 0);
      }

      // ---- mask + online softmax (per m) ----
      float P[2][4][4];
#pragma unroll
      for (int m = 0; m < 2; ++m) {
        float tm[4] = {-1e30f, -1e30f, -1e30f, -1e30f};
#pragma unroll
        for (int n = 0; n < 4; ++n) {
          const int kv = kv0 + n * 16 + fr;
#pragma unroll
          for (int j = 0; j < 4; ++j) {
            const int qi = q0 + wid * 32 + m * 16 + fq * 4 + j;
            const float s = (kv <= qi) ? S[m][n][j] : -1e30f;
            P[m][n][j] = s;
            tm[j] = fmaxf(tm[j], s);
          }
        }
#pragma unroll
        for (int j = 0; j < 4; ++j)
#pragma unroll
          for (int msk = 1; msk < 16; msk <<= 1)
            tm[j] = fmaxf(tm[j], __shfl_xor(tm[j], msk));

        float al[4], rs[4];
#pragma unroll
        for (int j = 0; j < 4; ++j) {
          const float mn = fmaxf(mrun[m][j], tm[j]);
          al[j] = __expf(mrun[m][j] - mn);
          mrun[m][j] = mn;
          rs[j] = 0.f;
        }
#pragma unroll
        for (int n = 0; n < 4; ++n)
#pragma unroll
          for (int j = 0; j < 4; ++j) {
            const float p = __expf(P[m][n][j] - mrun[m][j]);
            P[m][n][j] = p;
            rs[j] += p;
          }
#pragma unroll
        for (int j = 0; j < 4; ++j) {
#pragma unroll
          for (int msk = 1; msk < 16; msk <<= 1) rs[j] += __shfl_xor(rs[j], msk);
          lrun[m][j] = lrun[m][j] * al[j] + rs[j];
        }
#pragma unroll
        for (int f = 0; f < 8; ++f) {
          f32x4 o = Oacc[m][f];
#pragma unroll
          for (int j = 0; j < 4; ++j) o[j] *= al[j];
          Oacc[m][f] = o;
        }
      }

      // ---- P (C-layout) -> padded LDS -> A-layout ----
#pragma unroll
      for (int m = 0; m < 2; ++m)
#pragma unroll
        for (int n = 0; n < 4; ++n)
#pragma unroll
          for (int j = 0; j < 4; ++j)
            Ps[wid][(m * 16 + fq * 4 + j) * 72 + n * 16 + fr] = f2b(P[m][n][j]);

      // ---- PV: each V frag feeds both m blocks ----
#pragma unroll
      for (int kb = 0; kb < 2; ++kb) {
        short8 pa0 = *(const short8*)(Ps[wid] + (fr) * 72 + kb * 32 + fq * 8);
        short8 pa1 = *(const short8*)(Ps[wid] + (16 + fr) * 72 + kb * 32 + fq * 8);
#pragma unroll
        for (int f = 0; f < 8; ++f) {
          const int d = f * 16 + fr;
          const int p = (kb * 4 + fq) ^ (d & 7);
          short8 vf = *(const short8*)((const char*)Vts + d * 128 + p * 16);
          Oacc[0][f] = __builtin_amdgcn_mfma_f32_16x16x32_bf16(pa0, vf, Oacc[0][f], 0, 0, 0);
          Oacc[1][f] = __builtin_amdgcn_mfma_f32_16x16x32_bf16(pa1, vf, Oacc[1][f], 0, 0, 0);
        }
      }
    }
    __syncthreads();
  }

#pragma unroll
  for (int m = 0; m < 2; ++m)
#pragma unroll
    for (int j = 0; j < 4; ++j) {
      const float inv = 1.f / lrun[m][j];
      const long r = q0 + wid * 32 + m * 16 + fq * 4 + j;
#pragma unroll
      for (int f = 0; f < 8; ++f)
        Ob[r * 4096 + h * 128 + f * 16 + fr] = f2b(Oacc[m][f][j] * inv);
    }
}

// ---------------- launch ----------------------------------------------------
extern "C" void kernel_launch(void* const* d_in, const int* in_sizes, int n_in,
                              void* d_out, int out_size, void* d_ws, size_t ws_size,
                              hipStream_t stream) {
  const float* hs   = (const float*)d_in[0];   // (2048, 4096)
  const float* cosb = (const float*)d_in[1];   // (2048, 128)
  const float* sinb = (const float*)d_in[2];   // (2048, 128)
  const float* wp   = (const float*)d_in[3];   // (12288, 4096)
  const float* wo   = (const float*)d_in[4];   // (4096, 4096)
  float* out = (float*)d_out;                  // (2048, 4096)
  char* ws = (char*)d_ws;

  // workspace (180 MB peak):
  //   [0,16M)    h_bf   -> reused by attn output after GEMM1
  //   [16M,116M) wp_bf  -> reused by wo_bf after GEMM1
  //   [116M,164M) qkv (q,k written; v region unused)
  //   [164M,180M) vt (4096 x 2048, written by GEMM1 epilogue)
  u16* h_bf  = (u16*)(ws);
  u16* attn  = (u16*)(ws);
  u16* wp_bf = (u16*)(ws + 16777216);
  u16* wo_bf = (u16*)(ws + 16777216);
  u16* qkv   = (u16*)(ws + 121634816);
  u16* vt    = (u16*)(ws + 171966464);

  cvt_hp<<<4096, 256, 0, stream>>>(hs, wp, h_bf, wp_bf);
  gemm8p<<<512, 512, 0, stream>>>(h_bf, wp_bf, qkv, vt, 2048, 12288, 4096);
  cvt_bf16<<<2048, 256, 0, stream>>>(wo, wo_bf, 4194304);
  rope_qk<<<8192, 256, 0, stream>>>(qkv, cosb, sinb);
  attn_fwd<<<dim3(16, 32), 256, 0, stream>>>(qkv, qkv + 4096, vt, attn);
  gemm2_4p<<<256, 512, 0, stream>>>(attn, wo_bf, out, 2048, 4096, 4096);
}

// Round 10
// 456.365 us; speedup vs baseline: 1.1883x; 1.1883x over previous
//
#include <hip/hip_runtime.h>

typedef unsigned short u16;
typedef unsigned int   u32;
typedef __attribute__((ext_vector_type(8))) short short8;   // 8 x bf16
typedef __attribute__((ext_vector_type(4))) float f32x4;

__device__ __forceinline__ float b2f(u16 u) {
  union { float f; u32 i; } v; v.i = ((u32)u) << 16; return v.f;
}
__device__ __forceinline__ u16 f2b(float f) {
  union { float f; u32 i; } v; v.f = f;
  u32 r = v.i + 0x7fffu + ((v.i >> 16) & 1u);   // RNE
  return (u16)(r >> 16);
}

__device__ __forceinline__ void gload_lds16(const void* g, void* l) {
  __builtin_amdgcn_global_load_lds(
      (const __attribute__((address_space(1))) void*)g,
      (__attribute__((address_space(3))) void*)l, 16, 0, 0);
}

template <int N> __device__ __forceinline__ void wait_vmcnt() {
  if constexpr (N == 0)      asm volatile("s_waitcnt vmcnt(0)" ::: "memory");
  else if constexpr (N == 2) asm volatile("s_waitcnt vmcnt(2)" ::: "memory");
  else if constexpr (N == 3) asm volatile("s_waitcnt vmcnt(3)" ::: "memory");
  else if constexpr (N == 6) asm volatile("s_waitcnt vmcnt(6)" ::: "memory");
  else static_assert(N < 0, "unsupported vmcnt literal");
}

// ---------------- f32 -> bf16 converts ----------------
__device__ __forceinline__ ushort4 cvt4(float4 v) {
  ushort4 o;
  o.x = f2b(v.x); o.y = f2b(v.y); o.z = f2b(v.z); o.w = f2b(v.w);
  return o;
}

__global__ __launch_bounds__(256) void cvt_hp(const float* __restrict__ hs,
                                              const float* __restrict__ wp,
                                              u16* __restrict__ h_bf,
                                              u16* __restrict__ wp_bf) {
  const long H4 = 2097152, W4 = 12582912;   // float4 counts
  for (long i = (long)blockIdx.x * 256 + threadIdx.x; i < H4 + W4;
       i += (long)gridDim.x * 256) {
    if (i < H4)
      ((ushort4*)h_bf)[i] = cvt4(((const float4*)hs)[i]);
    else
      ((ushort4*)wp_bf)[i - H4] = cvt4(((const float4*)wp)[i - H4]);
  }
}

__global__ __launch_bounds__(256) void cvt_bf16(const float* __restrict__ in,
                                                u16* __restrict__ out, int n4) {
  for (long i = (long)blockIdx.x * 256 + threadIdx.x; i < n4; i += (long)gridDim.x * 256)
    ((ushort4*)out)[i] = cvt4(((const float4*)in)[i]);
}

__device__ __forceinline__ short8 frag_ld64(const u16* base, int rbase, int kk,
                                            int fr, int fq) {
  const int r = rbase + fr;
  return *(const short8*)(base + r * 64 + ((((kk << 2) + fq) ^ (r & 7)) << 3));
}

// ============ GEMM1: 4-phase, tile 256x192 (proven R7, unchanged) ==========
__global__ __launch_bounds__(512, 2) void gemm8p(const u16* __restrict__ A,
                                                 const u16* __restrict__ B,
                                                 u16* __restrict__ Cq,
                                                 u16* __restrict__ VT,
                                                 int M, int N, int K) {
  constexpr int AE = 16384;                 // A region u16 (256x64)
  constexpr int BUFSZ = AE + 12288;         // + B region (192x64) = 28672 u16
  __shared__ u16 lds[2 * BUFSZ];            // 114,688 B
  const int tid = threadIdx.x;
  const int wid = tid >> 6, lane = tid & 63;
  const int fr = lane & 15, fq = lane >> 4;
  const int mA = (wid >> 2) * 128;          // wm in {0,1}
  const int nB = (wid & 3) * 48;            // wn in {0..3}

  const int nty = M >> 8;                   // 8
  const int qx = gridDim.x >> 3;
  const int wg = (blockIdx.x & 7) * qx + (blockIdx.x >> 3);
  const int by = wg % nty, bx = wg / nty;
  const long row0 = (long)by * 256, col0 = (long)bx * 192;

  const int rr8 = tid >> 3;
  const int jl = (tid & 7) ^ (rr8 & 7);
  const u16* gA = A + (row0 + rr8) * (long)K + jl * 8;
  const u16* gB = B + (col0 + rr8) * (long)K + jl * 8;

  f32x4 acc[8][3];
#pragma unroll
  for (int m = 0; m < 8; ++m)
#pragma unroll
    for (int n = 0; n < 3; ++n) acc[m][n] = f32x4{0.f, 0.f, 0.f, 0.f};

  const int NT = K >> 6;                    // BK = 64

  auto stageA = [&](int i, int t) {
    gload_lds16(gA + (long)(i * 64) * K + (long)t * 64,
                lds + (t & 1) * BUFSZ + (i * 512 + tid) * 8);
  };
  auto stageB = [&](int i, int t) {
    gload_lds16(gB + (long)(i * 64) * K + (long)t * 64,
                lds + (t & 1) * BUFSZ + AE + (i * 512 + tid) * 8);
  };

#pragma unroll
  for (int i = 0; i < 4; ++i) stageA(i, 0);
#pragma unroll
  for (int i = 0; i < 3; ++i) stageB(i, 0);
#pragma unroll
  for (int i = 0; i < 3; ++i) stageB(i, 1);
  wait_vmcnt<3>();
  __builtin_amdgcn_s_barrier();

  for (int t = 0; t < NT; ++t) {
    const u16* SA = lds + (t & 1) * BUFSZ;
    const u16* SB = SA + AE;
    short8 a0[4], a1[4], b0[3], b1[3];

    // ---- phase 1: (qm0,kk0); all B frags; stage A i=0,1 ----
#pragma unroll
    for (int m = 0; m < 4; ++m) a0[m] = frag_ld64(SA, mA + m * 16, 0, fr, fq);
#pragma unroll
    for (int n = 0; n < 3; ++n) b0[n] = frag_ld64(SB, nB + n * 16, 0, fr, fq);
#pragma unroll
    for (int n = 0; n < 3; ++n) b1[n] = frag_ld64(SB, nB + n * 16, 1, fr, fq);
    if (t + 1 < NT) { stageA(0, t + 1); stageA(1, t + 1); }
    __builtin_amdgcn_s_setprio(1);
#pragma unroll
    for (int m = 0; m < 4; ++m)
#pragma unroll
      for (int n = 0; n < 3; ++n)
        acc[m][n] = __builtin_amdgcn_mfma_f32_16x16x32_bf16(a0[m], b0[n], acc[m][n], 0, 0, 0);
    __builtin_amdgcn_s_setprio(0);
    asm volatile("s_waitcnt lgkmcnt(0)" ::: "memory");   // all B(t) reads retired
    __builtin_amdgcn_s_barrier();

    // ---- phase 2: (qm1,kk0); stage A i=2,3 ----
#pragma unroll
    for (int m = 0; m < 4; ++m) a1[m] = frag_ld64(SA, mA + 64 + m * 16, 0, fr, fq);
    if (t + 1 < NT) { stageA(2, t + 1); stageA(3, t + 1); }
    __builtin_amdgcn_s_setprio(1);
#pragma unroll
    for (int m = 0; m < 4; ++m)
#pragma unroll
      for (int n = 0; n < 3; ++n)
        acc[4 + m][n] = __builtin_amdgcn_mfma_f32_16x16x32_bf16(a1[m], b0[n], acc[4 + m][n], 0, 0, 0);
    __builtin_amdgcn_s_setprio(0);
    __builtin_amdgcn_s_barrier();

    // ---- phase 3: (qm0,kk1); stage B i=0,1 into buf(t) B-region ----
#pragma unroll
    for (int m = 0; m < 4; ++m) a0[m] = frag_ld64(SA, mA + m * 16, 1, fr, fq);
    if (t + 2 < NT) { stageB(0, t + 2); stageB(1, t + 2); }
    __builtin_amdgcn_s_setprio(1);
#pragma unroll
    for (int m = 0; m < 4; ++m)
#pragma unroll
      for (int n = 0; n < 3; ++n)
        acc[m][n] = __builtin_amdgcn_mfma_f32_16x16x32_bf16(a0[m], b1[n], acc[m][n], 0, 0, 0);
    __builtin_amdgcn_s_setprio(0);
    __builtin_amdgcn_s_barrier();

    // ---- phase 4: (qm1,kk1); stage B i=2; counted vmcnt ----
#pragma unroll
    for (int m = 0; m < 4; ++m) a1[m] = frag_ld64(SA, mA + 64 + m * 16, 1, fr, fq);
    if (t + 2 < NT) stageB(2, t + 2);
    __builtin_amdgcn_s_setprio(1);
#pragma unroll
    for (int m = 0; m < 4; ++m)
#pragma unroll
      for (int n = 0; n < 3; ++n)
        acc[4 + m][n] = __builtin_amdgcn_mfma_f32_16x16x32_bf16(a1[m], b1[n], acc[4 + m][n], 0, 0, 0);
    __builtin_amdgcn_s_setprio(0);
    if (t + 2 < NT) wait_vmcnt<3>();
    else            wait_vmcnt<0>();
    __builtin_amdgcn_s_barrier();
  }

#pragma unroll
  for (int m = 0; m < 8; ++m)
#pragma unroll
    for (int n = 0; n < 3; ++n) {
      const long c = col0 + nB + n * 16 + fr;
      const long rb = row0 + mA + m * 16 + fq * 4;
      if (c >= 8192) {
        ushort4 o;
        o.x = f2b(acc[m][n][0]); o.y = f2b(acc[m][n][1]);
        o.z = f2b(acc[m][n][2]); o.w = f2b(acc[m][n][3]);
        *(ushort4*)(VT + (c - 8192) * 2048 + rb) = o;
      } else {
#pragma unroll
        for (int j = 0; j < 4; ++j) Cq[(rb + j) * N + c] = f2b(acc[m][n][j]);
      }
    }
}

// ============ GEMM2: 4-phase, tile 256x128 (R8, unchanged) ==================
__global__ __launch_bounds__(512, 2) void gemm2_4p(const u16* __restrict__ A,
                                                   const u16* __restrict__ B,
                                                   float* __restrict__ C,
                                                   int M, int N, int K) {
  constexpr int AE = 16384;                 // A region u16 (256x64)
  constexpr int BUFSZ = AE + 8192;          // + B region (128x64) = 24576 u16
  __shared__ u16 lds[2 * BUFSZ];            // 98,304 B
  const int tid = threadIdx.x;
  const int wid = tid >> 6, lane = tid & 63;
  const int fr = lane & 15, fq = lane >> 4;
  const int mA = (wid >> 2) * 128;          // wm in {0,1}
  const int nB = (wid & 3) * 32;            // wn in {0..3}

  const int nty = M >> 8;                   // 8
  const int qx = gridDim.x >> 3;
  const int wg = (blockIdx.x & 7) * qx + (blockIdx.x >> 3);
  const int by = wg % nty, bx = wg / nty;
  const long row0 = (long)by * 256, col0 = (long)bx * 128;

  const int rr8 = tid >> 3;
  const int jl = (tid & 7) ^ (rr8 & 7);
  const u16* gA = A + (row0 + rr8) * (long)K + jl * 8;
  const u16* gB = B + (col0 + rr8) * (long)K + jl * 8;

  f32x4 acc[8][2];
#pragma unroll
  for (int m = 0; m < 8; ++m)
#pragma unroll
    for (int n = 0; n < 2; ++n) acc[m][n] = f32x4{0.f, 0.f, 0.f, 0.f};

  const int NT = K >> 6;

  auto stageA = [&](int i, int t) {
    gload_lds16(gA + (long)(i * 64) * K + (long)t * 64,
                lds + (t & 1) * BUFSZ + (i * 512 + tid) * 8);
  };
  auto stageB = [&](int i, int t) {
    gload_lds16(gB + (long)(i * 64) * K + (long)t * 64,
                lds + (t & 1) * BUFSZ + AE + (i * 512 + tid) * 8);
  };

#pragma unroll
  for (int i = 0; i < 4; ++i) stageA(i, 0);
#pragma unroll
  for (int i = 0; i < 2; ++i) stageB(i, 0);
#pragma unroll
  for (int i = 0; i < 2; ++i) stageB(i, 1);
  wait_vmcnt<2>();
  __builtin_amdgcn_s_barrier();

  for (int t = 0; t < NT; ++t) {
    const u16* SA = lds + (t & 1) * BUFSZ;
    const u16* SB = SA + AE;
    short8 a0[4], a1[4], b0[2], b1[2];

    // ---- phase 1 ----
#pragma unroll
    for (int m = 0; m < 4; ++m) a0[m] = frag_ld64(SA, mA + m * 16, 0, fr, fq);
#pragma unroll
    for (int n = 0; n < 2; ++n) b0[n] = frag_ld64(SB, nB + n * 16, 0, fr, fq);
#pragma unroll
    for (int n = 0; n < 2; ++n) b1[n] = frag_ld64(SB, nB + n * 16, 1, fr, fq);
    if (t + 1 < NT) { stageA(0, t + 1); stageA(1, t + 1); }
    __builtin_amdgcn_s_setprio(1);
#pragma unroll
    for (int m = 0; m < 4; ++m)
#pragma unroll
      for (int n = 0; n < 2; ++n)
        acc[m][n] = __builtin_amdgcn_mfma_f32_16x16x32_bf16(a0[m], b0[n], acc[m][n], 0, 0, 0);
    __builtin_amdgcn_s_setprio(0);
    asm volatile("s_waitcnt lgkmcnt(0)" ::: "memory");   // all B(t) reads retired
    __builtin_amdgcn_s_barrier();

    // ---- phase 2 ----
#pragma unroll
    for (int m = 0; m < 4; ++m) a1[m] = frag_ld64(SA, mA + 64 + m * 16, 0, fr, fq);
    if (t + 1 < NT) { stageA(2, t + 1); stageA(3, t + 1); }
    __builtin_amdgcn_s_setprio(1);
#pragma unroll
    for (int m = 0; m < 4; ++m)
#pragma unroll
      for (int n = 0; n < 2; ++n)
        acc[4 + m][n] = __builtin_amdgcn_mfma_f32_16x16x32_bf16(a1[m], b0[n], acc[4 + m][n], 0, 0, 0);
    __builtin_amdgcn_s_setprio(0);
    __builtin_amdgcn_s_barrier();

    // ---- phase 3 ----
#pragma unroll
    for (int m = 0; m < 4; ++m) a0[m] = frag_ld64(SA, mA + m * 16, 1, fr, fq);
    if (t + 2 < NT) stageB(0, t + 2);
    __builtin_amdgcn_s_setprio(1);
#pragma unroll
    for (int m = 0; m < 4; ++m)
#pragma unroll
      for (int n = 0; n < 2; ++n)
        acc[m][n] = __builtin_amdgcn_mfma_f32_16x16x32_bf16(a0[m], b1[n], acc[m][n], 0, 0, 0);
    __builtin_amdgcn_s_setprio(0);
    __builtin_amdgcn_s_barrier();

    // ---- phase 4 ----
#pragma unroll
    for (int m = 0; m < 4; ++m) a1[m] = frag_ld64(SA, mA + 64 + m * 16, 1, fr, fq);
    if (t + 2 < NT) stageB(1, t + 2);
    __builtin_amdgcn_s_setprio(1);
#pragma unroll
    for (int m = 0; m < 4; ++m)
#pragma unroll
      for (int n = 0; n < 2; ++n)
        acc[4 + m][n] = __builtin_amdgcn_mfma_f32_16x16x32_bf16(a1[m], b1[n], acc[4 + m][n], 0, 0, 0);
    __builtin_amdgcn_s_setprio(0);
    if (t + 2 < NT) wait_vmcnt<2>();
    else            wait_vmcnt<0>();
    __builtin_amdgcn_s_barrier();
  }

#pragma unroll
  for (int m = 0; m < 8; ++m)
#pragma unroll
    for (int n = 0; n < 2; ++n)
#pragma unroll
      for (int j = 0; j < 4; ++j) {
        const long r = row0 + mA + m * 16 + fq * 4 + j;
        const long c = col0 + nB + n * 16 + fr;
        C[r * N + c] = acc[m][n][j];
      }
}

// ---------------- RoPE on q,k (vectorized) ---------------------------------
__global__ __launch_bounds__(256) void rope_qk(u16* __restrict__ qkv,
                                               const float* __restrict__ cosb,
                                               const float* __restrict__ sinb) {
  const int idx = blockIdx.x * 256 + threadIdx.x;   // grid exact: 2,097,152
  const int dq  = idx & 15;
  const int h   = (idx >> 4) & 31;
  const int seg = (idx >> 9) & 1;                   // 0 = q, 1 = k
  const int s   = idx >> 10;
  const int d0  = dq * 4;
  u16* base = qkv + (long)s * 12288 + seg * 4096 + h * 128;
  const ushort4 x1 = *(const ushort4*)(base + d0);
  const ushort4 x2 = *(const ushort4*)(base + d0 + 64);
  const float4 c1 = *(const float4*)(cosb + s * 128 + d0);
  const float4 s1 = *(const float4*)(sinb + s * 128 + d0);
  const float4 c2 = *(const float4*)(cosb + s * 128 + d0 + 64);
  const float4 s2 = *(const float4*)(sinb + s * 128 + d0 + 64);
  const float scale = seg ? 1.0f : 0.08838834764831845f;   // 1/sqrt(128) on q
  float x1f[4] = {b2f(x1.x), b2f(x1.y), b2f(x1.z), b2f(x1.w)};
  float x2f[4] = {b2f(x2.x), b2f(x2.y), b2f(x2.z), b2f(x2.w)};
  const float c1a[4] = {c1.x, c1.y, c1.z, c1.w}, s1a[4] = {s1.x, s1.y, s1.z, s1.w};
  const float c2a[4] = {c2.x, c2.y, c2.z, c2.w}, s2a[4] = {s2.x, s2.y, s2.z, s2.w};
  ushort4 o1, o2;
  u16* o1p = (u16*)&o1; u16* o2p = (u16*)&o2;
#pragma unroll
  for (int j = 0; j < 4; ++j) {
    o1p[j] = f2b((x1f[j] * c1a[j] - x2f[j] * s1a[j]) * scale);
    o2p[j] = f2b((x2f[j] * c2a[j] + x1f[j] * s2a[j]) * scale);
  }
  *(ushort4*)(base + d0) = o1;
  *(ushort4*)(base + d0 + 64) = o2;
}

// ------- causal flash attention: paired q-tiles (uniform work) + dbuf -------
// grid (8, 32), 256 thr = 4 waves. Block (p,h) processes q-tiles {p, 15-p}
// (QBLK=128) sequentially -> every block = 34 KV-tiles. K/V double-buffered:
// stage(t+1) issued before compute(t); one vmcnt(0)+barrier per tile.
__global__ __launch_bounds__(256) void attn_fwd(const u16* __restrict__ Qb,
                                                const u16* __restrict__ Kb,
                                                const u16* __restrict__ Vt,
                                                u16* __restrict__ Ob) {
  const int h = blockIdx.y;
  const int tid = threadIdx.x;
  const int wid = tid >> 6, lane = tid & 63;
  const int fr = lane & 15, fq = lane >> 4;

  __shared__ u16 Ks[2][64 * 128];    // 2 x 16 KB
  __shared__ u16 Vts[2][128 * 64];   // 2 x 16 KB
  __shared__ u16 Ps[4][32 * 72];     // 18.4 KB  (total 82.4 KB -> 1 block/CU)

  auto stage = [&](int t, int buf) {
    const int kv0 = t * 64;
#pragma unroll
    for (int i = 0; i < 4; ++i) {
      const int c = wid * 4 + i;
      {
        const int r = c * 4 + (lane >> 4);
        const int p = lane & 15;
        const int jsrc = p ^ (r & 7);
        gload_lds16(Kb + (long)(kv0 + r) * 12288 + h * 128 + jsrc * 8,
                    (char*)Ks[buf] + c * 1024);
      }
      {
        const int d = c * 8 + (lane >> 3);
        const int p = lane & 7;
        const int jsrc = p ^ (d & 7);
        gload_lds16(Vt + (long)(h * 128 + d) * 2048 + kv0 + jsrc * 8,
                    (char*)Vts[buf] + c * 1024);
      }
    }
  };

#pragma unroll
  for (int pass = 0; pass < 2; ++pass) {
    const int qt = pass == 0 ? (int)blockIdx.x : 15 - (int)blockIdx.x;
    const int q0 = qt * 128;
    const int nt = 2 * qt + 2;
    const int wq_hi = q0 + wid * 32 + 31;   // wave's max q row

    short8 qf[2][4];
#pragma unroll
    for (int m = 0; m < 2; ++m) {
      const long qrow = q0 + wid * 32 + m * 16 + fr;
#pragma unroll
      for (int kk = 0; kk < 4; ++kk)
        qf[m][kk] = *(const short8*)(Qb + qrow * 12288 + h * 128 + kk * 32 + fq * 8);
    }

    f32x4 Oacc[2][8];
#pragma unroll
    for (int m = 0; m < 2; ++m)
#pragma unroll
      for (int f = 0; f < 8; ++f) Oacc[m][f] = f32x4{0.f, 0.f, 0.f, 0.f};
    float mrun[2][4], lrun[2][4];
#pragma unroll
    for (int m = 0; m < 2; ++m)
#pragma unroll
      for (int j = 0; j < 4; ++j) { mrun[m][j] = -1e30f; lrun[m][j] = 0.f; }

    stage(0, 0);
    wait_vmcnt<0>();
    __builtin_amdgcn_s_barrier();

    for (int t = 0; t < nt; ++t) {
      const int cur = t & 1;
      const int kv0 = t * 64;
      if (t + 1 < nt) stage(t + 1, cur ^ 1);

      if (kv0 <= wq_hi) {                    // wave-uniform causal skip
        f32x4 S[2][4];
#pragma unroll
        for (int m = 0; m < 2; ++m)
#pragma unroll
          for (int n = 0; n < 4; ++n) S[m][n] = f32x4{0.f, 0.f, 0.f, 0.f};
#pragma unroll
        for (int kk = 0; kk < 4; ++kk) {
          short8 kf[4];
#pragma unroll
          for (int n = 0; n < 4; ++n) {
            const int r = n * 16 + fr;
            const int p = (kk * 4 + fq) ^ (r & 7);
            kf[n] = *(const short8*)((const char*)Ks[cur] + r * 256 + p * 16);
          }
#pragma unroll
          for (int m = 0; m < 2; ++m)
#pragma unroll
            for (int n = 0; n < 4; ++n)
              S[m][n] = __builtin_amdgcn_mfma_f32_16x16x32_bf16(qf[m][kk], kf[n], S[m][n], 0, 0, 0);
        }

        float P[2][4][4];
#pragma unroll
        for (int m = 0; m < 2; ++m) {
          float tm[4] = {-1e30f, -1e30f, -1e30f, -1e30f};
#pragma unroll
          for (int n = 0; n < 4; ++n) {
            const int kv = kv0 + n * 16 + fr;
#pragma unroll
            for (int j = 0; j < 4; ++j) {
              const int qi = q0 + wid * 32 + m * 16 + fq * 4 + j;
              const float s = (kv <= qi) ? S[m][n][j] : -1e30f;
              P[m][n][j] = s;
              tm[j] = fmaxf(tm[j], s);
            }
          }
#pragma unroll
          for (int j = 0; j < 4; ++j)
#pragma unroll
            for (int msk = 1; msk < 16; msk <<= 1)
              tm[j] = fmaxf(tm[j], __shfl_xor(tm[j], msk));

          float al[4], rs[4];
#pragma unroll
          for (int j = 0; j < 4; ++j) {
            const float mn = fmaxf(mrun[m][j], tm[j]);
            al[j] = __expf(mrun[m][j] - mn);
            mrun[m][j] = mn;
            rs[j] = 0.f;
          }
#pragma unroll
          for (int n = 0; n < 4; ++n)
#pragma unroll
            for (int j = 0; j < 4; ++j) {
              const float p = __expf(P[m][n][j] - mrun[m][j]);
              P[m][n][j] = p;
              rs[j] += p;
            }
#pragma unroll
          for (int j = 0; j < 4; ++j) {
#pragma unroll
            for (int msk = 1; msk < 16; msk <<= 1) rs[j] += __shfl_xor(rs[j], msk);
            lrun[m][j] = lrun[m][j] * al[j] + rs[j];
          }
#pragma unroll
          for (int f = 0; f < 8; ++f) {
            f32x4 o = Oacc[m][f];
#pragma unroll
            for (int j = 0; j < 4; ++j) o[j] *= al[j];
            Oacc[m][f] = o;
          }
        }

#pragma unroll
        for (int m = 0; m < 2; ++m)
#pragma unroll
          for (int n = 0; n < 4; ++n)
#pragma unroll
            for (int j = 0; j < 4; ++j)
              Ps[wid][(m * 16 + fq * 4 + j) * 72 + n * 16 + fr] = f2b(P[m][n][j]);

#pragma unroll
        for (int kb = 0; kb < 2; ++kb) {
          short8 pa0 = *(const short8*)(Ps[wid] + (fr) * 72 + kb * 32 + fq * 8);
          short8 pa1 = *(const short8*)(Ps[wid] + (16 + fr) * 72 + kb * 32 + fq * 8);
#pragma unroll
          for (int f = 0; f < 8; ++f) {
            const int d = f * 16 + fr;
            const int p = (kb * 4 + fq) ^ (d & 7);
            short8 vf = *(const short8*)((const char*)Vts[cur] + d * 128 + p * 16);
            Oacc[0][f] = __builtin_amdgcn_mfma_f32_16x16x32_bf16(pa0, vf, Oacc[0][f], 0, 0, 0);
            Oacc[1][f] = __builtin_amdgcn_mfma_f32_16x16x32_bf16(pa1, vf, Oacc[1][f], 0, 0, 0);
          }
        }
      }
      // stage(t+1) landed (issued at iter start, covered by this tile's compute)
      wait_vmcnt<0>();
      __builtin_amdgcn_s_barrier();
    }

#pragma unroll
    for (int m = 0; m < 2; ++m)
#pragma unroll
      for (int j = 0; j < 4; ++j) {
        const float inv = 1.f / lrun[m][j];
        const long r = q0 + wid * 32 + m * 16 + fq * 4 + j;
#pragma unroll
        for (int f = 0; f < 8; ++f)
          Ob[r * 4096 + h * 128 + f * 16 + fr] = f2b(Oacc[m][f][j] * inv);
      }
  }
}

// ---------------- launch ----------------------------------------------------
extern "C" void kernel_launch(void* const* d_in, const int* in_sizes, int n_in,
                              void* d_out, int out_size, void* d_ws, size_t ws_size,
                              hipStream_t stream) {
  const float* hs   = (const float*)d_in[0];   // (2048, 4096)
  const float* cosb = (const float*)d_in[1];   // (2048, 128)
  const float* sinb = (const float*)d_in[2];   // (2048, 128)
  const float* wp   = (const float*)d_in[3];   // (12288, 4096)
  const float* wo   = (const float*)d_in[4];   // (4096, 4096)
  float* out = (float*)d_out;                  // (2048, 4096)
  char* ws = (char*)d_ws;

  // workspace (180 MB peak):
  //   [0,16M)    h_bf   -> reused by attn output after GEMM1
  //   [16M,116M) wp_bf  -> reused by wo_bf after GEMM1
  //   [116M,164M) qkv (q,k written; v region unused)
  //   [164M,180M) vt (4096 x 2048, written by GEMM1 epilogue)
  u16* h_bf  = (u16*)(ws);
  u16* attn  = (u16*)(ws);
  u16* wp_bf = (u16*)(ws + 16777216);
  u16* wo_bf = (u16*)(ws + 16777216);
  u16* qkv   = (u16*)(ws + 121634816);
  u16* vt    = (u16*)(ws + 171966464);

  cvt_hp<<<4096, 256, 0, stream>>>(hs, wp, h_bf, wp_bf);
  gemm8p<<<512, 512, 0, stream>>>(h_bf, wp_bf, qkv, vt, 2048, 12288, 4096);
  cvt_bf16<<<2048, 256, 0, stream>>>(wo, wo_bf, 4194304);
  rope_qk<<<8192, 256, 0, stream>>>(qkv, cosb, sinb);
  attn_fwd<<<dim3(8, 32), 256, 0, stream>>>(qkv, qkv + 4096, vt, attn);
  gemm2_4p<<<256, 512, 0, stream>>>(attn, wo_bf, out, 2048, 4096, 4096);
}